// Round 9
// baseline (6758.626 us; speedup 1.0000x reference)
//
#include <hip/hip_runtime.h>

typedef __attribute__((ext_vector_type(4))) float f32x4;
typedef __attribute__((ext_vector_type(8))) short short8;
typedef __attribute__((ext_vector_type(8))) unsigned short ushort8;
typedef __attribute__((ext_vector_type(4))) unsigned short ushort4v;
typedef __attribute__((ext_vector_type(4))) unsigned int uint4v;
typedef unsigned short ushort;
typedef unsigned long long u64;

__device__ __forceinline__ ushort f2bf(float f) {
  union { float f; unsigned u; } v; v.f = f;
  unsigned u = v.u;
  return (ushort)((u + 0x7FFFu + ((u >> 16) & 1u)) >> 16);  // RNE
}
__device__ __forceinline__ float bf2f(ushort s) {
  union { unsigned u; float f; } v; v.u = ((unsigned)s) << 16;
  return v.f;
}

// raw LDS-only block barrier: no vmem drain (publish stores stay in flight)
#define LGKM_BAR() asm volatile("s_waitcnt lgkmcnt(0)\n\ts_barrier" ::: "memory")

// ---------------- prep kernels ----------------

// dst[c][r] = bf16(src[r][c]); src [R][C] f32, dst [C][R] bf16
__global__ void transpose_cvt(const float* __restrict__ src, ushort* __restrict__ dst,
                              int R, int C) {
  __shared__ float tile[32][33];
  int bx = blockIdx.x * 32;  // col in src
  int by = blockIdx.y * 32;  // row in src
  int tx = threadIdx.x, ty = threadIdx.y;
#pragma unroll
  for (int i = 0; i < 32; i += 8)
    tile[ty + i][tx] = src[(size_t)(by + ty + i) * C + bx + tx];
  __syncthreads();
#pragma unroll
  for (int i = 0; i < 32; i += 8)
    dst[(size_t)(bx + ty + i) * R + by + tx] = f2bf(tile[tx][ty + i]);
}

__global__ void concat_bias(const float* a, const float* b, const float* c, const float* d,
                            float* __restrict__ o) {
  int i = blockIdx.x * 256 + threadIdx.x;  // 4096 total
  int g = i >> 10, n = i & 1023;
  float v = (g == 0) ? a[n] : (g == 1) ? b[n] : (g == 2) ? c[n] : d[n];
  o[i] = v;
}

// tagged h0: slot i = (tag 0 << 32) | bf16(h0[2i+1])<<16 | bf16(h0[2i])
__global__ void init_tagged(const float* __restrict__ h0, u64* __restrict__ tb0) {
  int i = blockIdx.x * 256 + threadIdx.x;  // 32768 slots
  float a = h0[(size_t)2 * i], b = h0[(size_t)2 * i + 1];
  tb0[i] = (u64)((unsigned)f2bf(a) | ((unsigned)f2bf(b) << 16));
}

// ---------------- phase 1: xp = x @ Wx + b  (bf16 MFMA) ----------------
// X [32768][512] f32 (row = b*512+t), Bt = WxT [4096][512] bf16, Out [t*64+b][4096] bf16
__global__ __launch_bounds__(256) void gemm_xp(
    const float* __restrict__ X,
    const ushort* __restrict__ Bt,
    const float* __restrict__ bias,
    ushort* __restrict__ Out) {
  __shared__ ushort As[128][40];  // +8 pad kills bank conflicts
  __shared__ ushort Bs[128][40];
  const int tid = threadIdx.x;
  const int lane = tid & 63;
  const int wave = tid >> 6;
  const int wr = wave >> 1, wc = wave & 1;  // 2x2 wave grid, 64x64 each
  const int row0 = blockIdx.y * 128, col0 = blockIdx.x * 128;
  const int l15 = lane & 15, kg = (lane >> 4) * 8;
  f32x4 acc[4][4] = {};
  for (int k0 = 0; k0 < 512; k0 += 32) {
#pragma unroll
    for (int r = 0; r < 2; ++r) {
      int cid = tid + (r << 8);
      int row = cid >> 2, kch = (cid & 3) << 3;
      const float* ap = X + (size_t)(row0 + row) * 512 + k0 + kch;
      f32x4 v0 = *(const f32x4*)ap;
      f32x4 v1 = *(const f32x4*)(ap + 4);
      ushort8 w;
      w[0] = f2bf(v0.x); w[1] = f2bf(v0.y); w[2] = f2bf(v0.z); w[3] = f2bf(v0.w);
      w[4] = f2bf(v1.x); w[5] = f2bf(v1.y); w[6] = f2bf(v1.z); w[7] = f2bf(v1.w);
      *(ushort8*)&As[row][kch] = w;
      uint4v vb = *(const uint4v*)(Bt + (size_t)(col0 + row) * 512 + k0 + kch);
      *(uint4v*)&Bs[row][kch] = vb;
    }
    __syncthreads();
    short8 af[4], bfv[4];
#pragma unroll
    for (int fm = 0; fm < 4; ++fm)
      af[fm] = *(const short8*)&As[wr * 64 + fm * 16 + l15][kg];
#pragma unroll
    for (int fn = 0; fn < 4; ++fn)
      bfv[fn] = *(const short8*)&Bs[wc * 64 + fn * 16 + l15][kg];
#pragma unroll
    for (int fm = 0; fm < 4; ++fm)
#pragma unroll
      for (int fn = 0; fn < 4; ++fn)
        acc[fm][fn] = __builtin_amdgcn_mfma_f32_16x16x32_bf16(af[fm], bfv[fn], acc[fm][fn], 0, 0, 0);
    __syncthreads();
  }
#pragma unroll
  for (int fm = 0; fm < 4; ++fm) {
#pragma unroll
    for (int fn = 0; fn < 4; ++fn) {
#pragma unroll
      for (int r = 0; r < 4; ++r) {
        int gr = row0 + wr * 64 + fm * 16 + ((lane >> 4) << 2) + r;  // D row
        int gc = col0 + wc * 64 + fn * 16 + l15;                     // D col
        int b = gr >> 9, t = gr & 511;                               // gr = b*512 + t
        Out[(size_t)(t * 64 + b) * 4096 + gc] = f2bf(acc[fm][fn][r] + bias[gc]);
      }
    }
  }
}

// ---------------- phase 2: persistent recurrence, tag-embedded h ----------------
// grid = 256 blocks: bg = blk>>7 (batch half, 32), s = blk&127 (8 units: n = s*8+u)
// h exchange: tb[parity][64 batch][512 slots] u64; slot j = (tag<<32) | units(2j,2j+1).
// Poll fast path: 32 x dwordx4 sc1 loads (2 tagged slots each) in 4 groups of 8,
// 2-deep pipelined with counted vmcnt(8) (in-order retirement -> "everything
// older than the last 8 is done"), so the whole first pass costs ~1 IF RTT.
// va/vb are unconditionally written fixed arrays (SROA-safe; NOT live across
// barriers). Stragglers fall to a rare per-granule atomic-u64 slow path.
__global__ __launch_bounds__(256) void lstm_rec(
    const ushort* __restrict__ xp,   // [512*64][4096] bf16, row = t*64+b
    const ushort* __restrict__ whT,  // [4096][1024] bf16 (gate-major cols)
    const float* __restrict__ c0,
    const float* __restrict__ wcf,
    const float* __restrict__ wci,
    const float* __restrict__ wco,
    u64* __restrict__ tb,            // [2][64][512] tagged slots
    float* __restrict__ out) {       // [64][512][1024] f32
  __shared__ ushort wh_s[32][1032];  // [col][k], +8 pad
  __shared__ ushort h_s[32][1032];   // [batch][k], +8 pad
  __shared__ float G[4][32][32];     // per-wave partial gates [w][batch][col]

  const int tid = threadIdx.x;
  const int blk = blockIdx.x;
  const int bg = blk >> 7;
  const int s = blk & 127;
  const int lane = tid & 63;
  const int wave = tid >> 6;

  // load Wh slice once: block col c -> global col (c>>3)*1024 + s*8 + (c&7)
#pragma unroll
  for (int r = 0; r < 16; ++r) {
    int cid = tid + (r << 8);
    int c = cid >> 7, kc = cid & 127;
    int gcol = ((c >> 3) << 10) + s * 8 + (c & 7);
    uint4v v = *(const uint4v*)(whT + (size_t)gcol * 1024 + kc * 8);
    *(uint4v*)&wh_s[c][kc * 8] = v;
  }

  const int b_l = tid >> 3;  // 0..31
  const int u = tid & 7;     // 0..7
  const int bG = bg * 32 + b_l;
  const int n = s * 8 + u;
  float c_val = c0[(size_t)bG * 1024 + n];
  const float pf = wcf[n], pi = wci[n], po = wco[n];

  const int l15 = lane & 15;
  const int kg = (lane >> 4) * 8;
  const int lq = lane & 15;     // granule col within chunk (16 per row)
  const int rbase = lane >> 4;  // row sub-index (0..3)
  const int bg32 = bg * 32;

  // prefetch xp for t=0
  const size_t xbase0 = (size_t)bG * 4096 + n;
  ushort px0 = xp[xbase0], px1 = xp[xbase0 + 1024];
  ushort px2 = xp[xbase0 + 2048], px3 = xp[xbase0 + 3072];

  __syncthreads();

  for (int t = 0; t < 512; ++t) {
    // ---- poll+stage own K-window: 16B granules, counted-vmcnt pipeline ----
    {
      const unsigned target = (unsigned)t;
      const u64* tbuf = tb + ((size_t)(t & 1) << 15);
      unsigned done = 0;
      uint4v va[8], vb[8];

#define GADDR(c, k)                                                            \
      (tbuf + (((size_t)(bg32 + ((k) << 2) + rbase)) << 9) +                   \
       (((wave << 2) + (c)) << 5) + ((lq) << 1))
#define ISSUE8(V, c)                                                           \
      _Pragma("unroll") for (int k = 0; k < 8; ++k) {                          \
        asm volatile("global_load_dwordx4 %0, %1, off sc1"                     \
                     : "=v"(V[k]) : "v"(GADDR(c, k)) : "memory");              \
      }
#define WAITN(N)                                                               \
      do {                                                                     \
        asm volatile("s_waitcnt vmcnt(" #N ")" ::: "memory");                  \
        __builtin_amdgcn_sched_barrier(0);                                     \
      } while (0)
#define CHECK8(V, c)                                                           \
      _Pragma("unroll") for (int k = 0; k < 8; ++k) {                          \
        uint4v v_ = V[k];                                                      \
        if (v_.y == target && v_.w == target) {                                \
          *(u64*)&h_s[((k) << 2) + rbase]                                      \
                     [(((wave << 2) + (c)) << 6) + ((lq) << 2)] =              \
              (u64)v_.x | ((u64)v_.z << 32);                                   \
          done |= 1u << ((c) * 8 + (k));                                       \
        }                                                                      \
      }

      ISSUE8(va, 0);
      ISSUE8(vb, 1);
      WAITN(8);  CHECK8(va, 0);
      ISSUE8(va, 2);
      WAITN(8);  CHECK8(vb, 1);
      ISSUE8(vb, 3);
      WAITN(8);  CHECK8(va, 2);
      WAITN(0);  CHECK8(vb, 3);

      // slow path: rare stragglers, per-granule atomic u64 loads
      while (__ballot(done != 0xFFFFFFFFu)) {
#pragma unroll
        for (int c = 0; c < 4; ++c) {
#pragma unroll
          for (int k = 0; k < 8; ++k) {
            if (!((done >> (c * 8 + k)) & 1u)) {
              const u64* p = GADDR(c, k);
              u64 s0 = __hip_atomic_load(p, __ATOMIC_RELAXED, __HIP_MEMORY_SCOPE_AGENT);
              u64 s1 = __hip_atomic_load(p + 1, __ATOMIC_RELAXED, __HIP_MEMORY_SCOPE_AGENT);
              if ((unsigned)(s0 >> 32) == target && (unsigned)(s1 >> 32) == target) {
                *(u64*)&h_s[(k << 2) + rbase]
                           [(((wave << 2) + c) << 6) + (lq << 2)] =
                    (u64)(unsigned)s0 | (((u64)(unsigned)s1) << 32);
                done |= 1u << (c * 8 + k);
              }
            }
          }
        }
        __builtin_amdgcn_s_sleep(1);
      }
#undef GADDR
#undef ISSUE8
#undef WAITN
#undef CHECK8
    }
    asm volatile("s_waitcnt lgkmcnt(0)" ::: "memory");  // staged LDS writes done
    __builtin_amdgcn_sched_barrier(0);

    // ---- MFMA own K-window (4 chunks x 2 k-steps x 4 tiles) ----
    f32x4 a00 = {}, a01 = {}, a10 = {}, a11 = {};
#pragma unroll
    for (int c = 0; c < 4; ++c) {
#pragma unroll
      for (int kk = 0; kk < 2; ++kk) {
        const int ko = (((wave << 2) + c) << 6) + (kk << 5) + kg;
        short8 fa0 = *(const short8*)&h_s[l15][ko];
        short8 fa1 = *(const short8*)&h_s[16 + l15][ko];
        short8 fb0 = *(const short8*)&wh_s[l15][ko];
        short8 fb1 = *(const short8*)&wh_s[16 + l15][ko];
        a00 = __builtin_amdgcn_mfma_f32_16x16x32_bf16(fa0, fb0, a00, 0, 0, 0);
        a01 = __builtin_amdgcn_mfma_f32_16x16x32_bf16(fa0, fb1, a01, 0, 0, 0);
        a10 = __builtin_amdgcn_mfma_f32_16x16x32_bf16(fa1, fb0, a10, 0, 0, 0);
        a11 = __builtin_amdgcn_mfma_f32_16x16x32_bf16(fa1, fb1, a11, 0, 0, 0);
      }
    }

    // ---- write per-wave partial gates ----
#pragma unroll
    for (int r = 0; r < 4; ++r) {
      const int rr = ((lane >> 4) << 2) + r;
      G[wave][rr][l15]           = a00[r];
      G[wave][rr][16 + l15]      = a01[r];
      G[wave][16 + rr][l15]      = a10[r];
      G[wave][16 + rr][16 + l15] = a11[r];
    }
    LGKM_BAR();  // sync#1: G partials ready (LDS-only, no vmem drain)

    // ---- elementwise gate update: one (batch, unit) per thread ----
    float gf = (G[0][b_l][u]      + G[1][b_l][u])      + (G[2][b_l][u]      + G[3][b_l][u])      + bf2f(px0);
    float gi = (G[0][b_l][8 + u]  + G[1][b_l][8 + u])  + (G[2][b_l][8 + u]  + G[3][b_l][8 + u])  + bf2f(px1);
    float go = (G[0][b_l][16 + u] + G[1][b_l][16 + u]) + (G[2][b_l][16 + u] + G[3][b_l][16 + u]) + bf2f(px2);
    float gc = (G[0][b_l][24 + u] + G[1][b_l][24 + u]) + (G[2][b_l][24 + u] + G[3][b_l][24 + u]) + bf2f(px3);
    float f = 1.f / (1.f + __expf(-(gf + pf * c_val)));
    float i = 1.f / (1.f + __expf(-(gi + pi * c_val)));
    float ct = 2.f / (1.f + __expf(-2.f * gc)) - 1.f;
    float cn = f * c_val + i * ct;
    float o = 1.f / (1.f + __expf(-(go + po * cn)));
    float h = o * (2.f / (1.f + __expf(-2.f * cn)) - 1.f);
    c_val = cn;

    // ---- publish h ASAP: ONE tagged sc1 store per even thread, fire-and-forget ----
    if (t < 511) {
      float hx = __shfl_xor(h, 1);
      if ((u & 1) == 0) {
        u64 val = (u64)((unsigned)f2bf(h) | ((unsigned)f2bf(hx) << 16)) |
                  ((u64)(unsigned)(t + 1) << 32);
        u64* dst = tb + ((size_t)((t + 1) & 1) << 15) + ((size_t)bG << 9) +
                   (s << 2) + (u >> 1);
        __hip_atomic_store(dst, val, __ATOMIC_RELAXED, __HIP_MEMORY_SCOPE_AGENT);
      }
    }
    LGKM_BAR();  // sync#2: G(t) reads done before next iter's G writes

    // off critical path: out store (non-temporal) + next xp prefetch
    __builtin_nontemporal_store(h, &out[(size_t)(bG * 512 + t) * 1024 + n]);
    if (t < 511) {
      size_t xb = xbase0 + (size_t)(t + 1) * 262144;  // 64*4096
      px0 = xp[xb]; px1 = xp[xb + 1024]; px2 = xp[xb + 2048]; px3 = xp[xb + 3072];
    }
  }
}

// ---------------- launcher ----------------
extern "C" void kernel_launch(void* const* d_in, const int* in_sizes, int n_in,
                              void* d_out, int out_size, void* d_ws, size_t ws_size,
                              hipStream_t stream) {
  const float* x = (const float*)d_in[0];
  const float* c0 = (const float*)d_in[1];
  const float* h0 = (const float*)d_in[2];
  const float* Wfx = (const float*)d_in[3];
  const float* bfp = (const float*)d_in[4];
  const float* Wix = (const float*)d_in[5];
  const float* bip = (const float*)d_in[6];
  const float* Wox = (const float*)d_in[7];
  const float* bop = (const float*)d_in[8];
  const float* Wcx = (const float*)d_in[9];
  const float* bcp = (const float*)d_in[10];
  const float* Wfh = (const float*)d_in[11];
  const float* Wih = (const float*)d_in[12];
  const float* Woh = (const float*)d_in[13];
  const float* Wch = (const float*)d_in[14];
  const float* wcf = (const float*)d_in[15];
  const float* wci = (const float*)d_in[16];
  const float* wco = (const float*)d_in[17];
  float* out = (float*)d_out;

  char* ws = (char*)d_ws;
  ushort* xp = (ushort*)(ws + 0);              // 268,435,456 B
  ushort* WxT = (ushort*)(ws + 268435456ULL);  // 4,194,304 B (dead after gemm_xp)
  u64* tb = (u64*)(ws + 268435456ULL);         // 524,288 B, REUSES WxT region
  ushort* WhT = (ushort*)(ws + 272629760ULL);  // 8,388,608 B
  float* bias = (float*)(ws + 281018368ULL);   // 16,384 B
  if (ws_size < 281034752ULL) return;

  const float* wxs[4] = {Wfx, Wix, Wox, Wcx};
  for (int g = 0; g < 4; ++g)
    transpose_cvt<<<dim3(32, 16), dim3(32, 8), 0, stream>>>(
        wxs[g], WxT + (size_t)g * 1024 * 512, 512, 1024);
  const float* whs[4] = {Wfh, Wih, Woh, Wch};
  for (int g = 0; g < 4; ++g)
    transpose_cvt<<<dim3(32, 32), dim3(32, 8), 0, stream>>>(
        whs[g], WhT + (size_t)g * 1024 * 1024, 1024, 1024);
  concat_bias<<<16, 256, 0, stream>>>(bfp, bip, bop, bcp, bias);
  gemm_xp<<<dim3(32, 256), 256, 0, stream>>>(x, WxT, bias, xp);

  // WxT is dead now; its region becomes the tagged h buffer.
  hipMemsetAsync(tb, 0xFF, 524288, stream);              // tags -> 0xFFFFFFFF
  init_tagged<<<128, 256, 0, stream>>>(h0, (u64*)tb);    // parity 0 <- h0, tag 0

  void* args[8];
  args[0] = (void*)&xp;
  args[1] = (void*)&WhT;
  args[2] = (void*)&c0;
  args[3] = (void*)&wcf;
  args[4] = (void*)&wci;
  args[5] = (void*)&wco;
  args[6] = (void*)&tb;
  args[7] = (void*)&out;
  hipLaunchCooperativeKernel((void*)lstm_rec, dim3(256), dim3(256), args, 0, stream);
}

// Round 10
// 2562.806 us; speedup vs baseline: 2.6372x; 2.6372x over previous
//
#include <hip/hip_runtime.h>

typedef __attribute__((ext_vector_type(4))) float f32x4;
typedef __attribute__((ext_vector_type(8))) short short8;
typedef __attribute__((ext_vector_type(8))) unsigned short ushort8;
typedef __attribute__((ext_vector_type(4))) unsigned short ushort4v;
typedef __attribute__((ext_vector_type(4))) unsigned int uint4v;
typedef unsigned short ushort;
typedef unsigned long long u64;

__device__ __forceinline__ ushort f2bf(float f) {
  union { float f; unsigned u; } v; v.f = f;
  unsigned u = v.u;
  return (ushort)((u + 0x7FFFu + ((u >> 16) & 1u)) >> 16);  // RNE
}
__device__ __forceinline__ float bf2f(ushort s) {
  union { unsigned u; float f; } v; v.u = ((unsigned)s) << 16;
  return v.f;
}

// raw LDS-only block barrier: no vmem drain (publish stores stay in flight)
#define LGKM_BAR() asm volatile("s_waitcnt lgkmcnt(0)\n\ts_barrier" ::: "memory")

// ---------------- prep kernels ----------------

// dst[c][r] = bf16(src[r][c]); src [R][C] f32, dst [C][R] bf16
__global__ void transpose_cvt(const float* __restrict__ src, ushort* __restrict__ dst,
                              int R, int C) {
  __shared__ float tile[32][33];
  int bx = blockIdx.x * 32;  // col in src
  int by = blockIdx.y * 32;  // row in src
  int tx = threadIdx.x, ty = threadIdx.y;
#pragma unroll
  for (int i = 0; i < 32; i += 8)
    tile[ty + i][tx] = src[(size_t)(by + ty + i) * C + bx + tx];
  __syncthreads();
#pragma unroll
  for (int i = 0; i < 32; i += 8)
    dst[(size_t)(bx + ty + i) * R + by + tx] = f2bf(tile[tx][ty + i]);
}

__global__ void concat_bias(const float* a, const float* b, const float* c, const float* d,
                            float* __restrict__ o) {
  int i = blockIdx.x * 256 + threadIdx.x;  // 4096 total
  int g = i >> 10, n = i & 1023;
  float v = (g == 0) ? a[n] : (g == 1) ? b[n] : (g == 2) ? c[n] : d[n];
  o[i] = v;
}

// tagged h0: slot i = (tag 0 << 32) | bf16(h0[2i+1])<<16 | bf16(h0[2i])
__global__ void init_tagged(const float* __restrict__ h0, u64* __restrict__ tb0) {
  int i = blockIdx.x * 256 + threadIdx.x;  // 32768 slots
  float a = h0[(size_t)2 * i], b = h0[(size_t)2 * i + 1];
  tb0[i] = (u64)((unsigned)f2bf(a) | ((unsigned)f2bf(b) << 16));
}

// ---------------- phase 1: xp = x @ Wx + b  (bf16 MFMA) ----------------
// X [32768][512] f32 (row = b*512+t), Bt = WxT [4096][512] bf16, Out [t*64+b][4096] bf16
__global__ __launch_bounds__(256) void gemm_xp(
    const float* __restrict__ X,
    const ushort* __restrict__ Bt,
    const float* __restrict__ bias,
    ushort* __restrict__ Out) {
  __shared__ ushort As[128][40];  // +8 pad kills bank conflicts
  __shared__ ushort Bs[128][40];
  const int tid = threadIdx.x;
  const int lane = tid & 63;
  const int wave = tid >> 6;
  const int wr = wave >> 1, wc = wave & 1;  // 2x2 wave grid, 64x64 each
  const int row0 = blockIdx.y * 128, col0 = blockIdx.x * 128;
  const int l15 = lane & 15, kg = (lane >> 4) * 8;
  f32x4 acc[4][4] = {};
  for (int k0 = 0; k0 < 512; k0 += 32) {
#pragma unroll
    for (int r = 0; r < 2; ++r) {
      int cid = tid + (r << 8);
      int row = cid >> 2, kch = (cid & 3) << 3;
      const float* ap = X + (size_t)(row0 + row) * 512 + k0 + kch;
      f32x4 v0 = *(const f32x4*)ap;
      f32x4 v1 = *(const f32x4*)(ap + 4);
      ushort8 w;
      w[0] = f2bf(v0.x); w[1] = f2bf(v0.y); w[2] = f2bf(v0.z); w[3] = f2bf(v0.w);
      w[4] = f2bf(v1.x); w[5] = f2bf(v1.y); w[6] = f2bf(v1.z); w[7] = f2bf(v1.w);
      *(ushort8*)&As[row][kch] = w;
      uint4v vb = *(const uint4v*)(Bt + (size_t)(col0 + row) * 512 + k0 + kch);
      *(uint4v*)&Bs[row][kch] = vb;
    }
    __syncthreads();
    short8 af[4], bfv[4];
#pragma unroll
    for (int fm = 0; fm < 4; ++fm)
      af[fm] = *(const short8*)&As[wr * 64 + fm * 16 + l15][kg];
#pragma unroll
    for (int fn = 0; fn < 4; ++fn)
      bfv[fn] = *(const short8*)&Bs[wc * 64 + fn * 16 + l15][kg];
#pragma unroll
    for (int fm = 0; fm < 4; ++fm)
#pragma unroll
      for (int fn = 0; fn < 4; ++fn)
        acc[fm][fn] = __builtin_amdgcn_mfma_f32_16x16x32_bf16(af[fm], bfv[fn], acc[fm][fn], 0, 0, 0);
    __syncthreads();
  }
#pragma unroll
  for (int fm = 0; fm < 4; ++fm) {
#pragma unroll
    for (int fn = 0; fn < 4; ++fn) {
#pragma unroll
      for (int r = 0; r < 4; ++r) {
        int gr = row0 + wr * 64 + fm * 16 + ((lane >> 4) << 2) + r;  // D row
        int gc = col0 + wc * 64 + fn * 16 + l15;                     // D col
        int b = gr >> 9, t = gr & 511;                               // gr = b*512 + t
        Out[(size_t)(t * 64 + b) * 4096 + gc] = f2bf(acc[fm][fn][r] + bias[gc]);
      }
    }
  }
}

// ---------------- phase 2: persistent recurrence, tag-embedded h ----------------
// grid = 256 blocks: bg = blk>>7 (batch half, 32), s = blk&127 (8 units: n = s*8+u)
// h exchange: tb[parity][64 batch][512 slots] u64; slot j = (tag<<32) | units(2j,2j+1).
// Poll pass 1: 32 x dwordx4 sc1 loads (2 tagged slots each), 4 groups of 8,
// 2-deep counted-vmcnt pipeline -> ~1 IF RTT. Retry passes: SAME clustered
// shape, but groups re-issued only if any lane still misses a granule in them
// (wave-uniform ballot -> clean s_cbranch, loads stay clustered), vmcnt(0)
// drain per 2-group phase -> ~2 RTTs/retry. No serialized per-granule path.
__global__ __launch_bounds__(256) void lstm_rec(
    const ushort* __restrict__ xp,   // [512*64][4096] bf16, row = t*64+b
    const ushort* __restrict__ whT,  // [4096][1024] bf16 (gate-major cols)
    const float* __restrict__ c0,
    const float* __restrict__ wcf,
    const float* __restrict__ wci,
    const float* __restrict__ wco,
    u64* __restrict__ tb,            // [2][64][512] tagged slots
    float* __restrict__ out) {       // [64][512][1024] f32
  __shared__ ushort wh_s[32][1032];  // [col][k], +8 pad
  __shared__ ushort h_s[32][1032];   // [batch][k], +8 pad
  __shared__ float G[4][32][32];     // per-wave partial gates [w][batch][col]

  const int tid = threadIdx.x;
  const int blk = blockIdx.x;
  const int bg = blk >> 7;
  const int s = blk & 127;
  const int lane = tid & 63;
  const int wave = tid >> 6;

  // load Wh slice once: block col c -> global col (c>>3)*1024 + s*8 + (c&7)
#pragma unroll
  for (int r = 0; r < 16; ++r) {
    int cid = tid + (r << 8);
    int c = cid >> 7, kc = cid & 127;
    int gcol = ((c >> 3) << 10) + s * 8 + (c & 7);
    uint4v v = *(const uint4v*)(whT + (size_t)gcol * 1024 + kc * 8);
    *(uint4v*)&wh_s[c][kc * 8] = v;
  }

  const int b_l = tid >> 3;  // 0..31
  const int u = tid & 7;     // 0..7
  const int bG = bg * 32 + b_l;
  const int n = s * 8 + u;
  float c_val = c0[(size_t)bG * 1024 + n];
  const float pf = wcf[n], pi = wci[n], po = wco[n];

  const int l15 = lane & 15;
  const int kg = (lane >> 4) * 8;
  const int lq = lane & 15;     // granule col within chunk (16 per row)
  const int rbase = lane >> 4;  // row sub-index (0..3)
  const int bg32 = bg * 32;

  // prefetch xp for t=0
  const size_t xbase0 = (size_t)bG * 4096 + n;
  ushort px0 = xp[xbase0], px1 = xp[xbase0 + 1024];
  ushort px2 = xp[xbase0 + 2048], px3 = xp[xbase0 + 3072];

  __syncthreads();

  for (int t = 0; t < 512; ++t) {
    // ---- poll+stage own K-window: 16B granules, clustered passes ----
    {
      const unsigned target = (unsigned)t;
      const u64* tbuf = tb + ((size_t)(t & 1) << 15);
      unsigned done = 0;
      uint4v va[8], vb[8];

#define GADDR(c, k)                                                            \
      (tbuf + (((size_t)(bg32 + ((k) << 2) + rbase)) << 9) +                   \
       (((wave << 2) + (c)) << 5) + ((lq) << 1))
#define ISSUE8(V, c)                                                           \
      _Pragma("unroll") for (int k = 0; k < 8; ++k) {                          \
        asm volatile("global_load_dwordx4 %0, %1, off sc1"                     \
                     : "=v"(V[k]) : "v"(GADDR(c, k)) : "memory");              \
      }
#define WAITN(N)                                                               \
      do {                                                                     \
        asm volatile("s_waitcnt vmcnt(" #N ")" ::: "memory");                  \
        __builtin_amdgcn_sched_barrier(0);                                     \
      } while (0)
#define CHECK8(V, c)                                                           \
      _Pragma("unroll") for (int k = 0; k < 8; ++k) {                          \
        uint4v v_ = V[k];                                                      \
        if (v_.y == target && v_.w == target) {                                \
          *(u64*)&h_s[((k) << 2) + rbase]                                      \
                     [(((wave << 2) + (c)) << 6) + ((lq) << 2)] =              \
              (u64)v_.x | ((u64)v_.z << 32);                                   \
          done |= 1u << ((c) * 8 + (k));                                       \
        }                                                                      \
      }

      // pass 1: unconditional, 2-deep counted pipeline (~1 RTT)
      ISSUE8(va, 0);
      ISSUE8(vb, 1);
      WAITN(8);  CHECK8(va, 0);
      ISSUE8(va, 2);
      WAITN(8);  CHECK8(vb, 1);
      ISSUE8(vb, 3);
      WAITN(8);  CHECK8(va, 2);
      WAITN(0);  CHECK8(vb, 3);

      // retry passes: same clustered shape, group-conditional (wave-uniform)
      while (__ballot(done != 0xFFFFFFFFu)) {
        __builtin_amdgcn_s_sleep(1);
        const unsigned miss = ~done;
        const bool a0 = __ballot(miss & 0x000000FFu) != 0ull;
        const bool a1 = __ballot(miss & 0x0000FF00u) != 0ull;
        const bool a2 = __ballot(miss & 0x00FF0000u) != 0ull;
        const bool a3 = __ballot(miss & 0xFF000000u) != 0ull;
        if (a0) ISSUE8(va, 0);
        if (a1) ISSUE8(vb, 1);
        WAITN(0);
        if (a0) CHECK8(va, 0);
        if (a1) CHECK8(vb, 1);
        if (a2) ISSUE8(va, 2);
        if (a3) ISSUE8(vb, 3);
        WAITN(0);
        if (a2) CHECK8(va, 2);
        if (a3) CHECK8(vb, 3);
      }
#undef GADDR
#undef ISSUE8
#undef WAITN
#undef CHECK8
    }
    asm volatile("s_waitcnt lgkmcnt(0)" ::: "memory");  // staged LDS writes done
    __builtin_amdgcn_sched_barrier(0);

    // ---- MFMA own K-window (4 chunks x 2 k-steps x 4 tiles) ----
    f32x4 a00 = {}, a01 = {}, a10 = {}, a11 = {};
#pragma unroll
    for (int c = 0; c < 4; ++c) {
#pragma unroll
      for (int kk = 0; kk < 2; ++kk) {
        const int ko = (((wave << 2) + c) << 6) + (kk << 5) + kg;
        short8 fa0 = *(const short8*)&h_s[l15][ko];
        short8 fa1 = *(const short8*)&h_s[16 + l15][ko];
        short8 fb0 = *(const short8*)&wh_s[l15][ko];
        short8 fb1 = *(const short8*)&wh_s[16 + l15][ko];
        a00 = __builtin_amdgcn_mfma_f32_16x16x32_bf16(fa0, fb0, a00, 0, 0, 0);
        a01 = __builtin_amdgcn_mfma_f32_16x16x32_bf16(fa0, fb1, a01, 0, 0, 0);
        a10 = __builtin_amdgcn_mfma_f32_16x16x32_bf16(fa1, fb0, a10, 0, 0, 0);
        a11 = __builtin_amdgcn_mfma_f32_16x16x32_bf16(fa1, fb1, a11, 0, 0, 0);
      }
    }

    // ---- write per-wave partial gates ----
#pragma unroll
    for (int r = 0; r < 4; ++r) {
      const int rr = ((lane >> 4) << 2) + r;
      G[wave][rr][l15]           = a00[r];
      G[wave][rr][16 + l15]      = a01[r];
      G[wave][16 + rr][l15]      = a10[r];
      G[wave][16 + rr][16 + l15] = a11[r];
    }
    LGKM_BAR();  // sync#1: G partials ready (LDS-only, no vmem drain)

    // ---- elementwise gate update: one (batch, unit) per thread ----
    float gf = (G[0][b_l][u]      + G[1][b_l][u])      + (G[2][b_l][u]      + G[3][b_l][u])      + bf2f(px0);
    float gi = (G[0][b_l][8 + u]  + G[1][b_l][8 + u])  + (G[2][b_l][8 + u]  + G[3][b_l][8 + u])  + bf2f(px1);
    float go = (G[0][b_l][16 + u] + G[1][b_l][16 + u]) + (G[2][b_l][16 + u] + G[3][b_l][16 + u]) + bf2f(px2);
    float gc = (G[0][b_l][24 + u] + G[1][b_l][24 + u]) + (G[2][b_l][24 + u] + G[3][b_l][24 + u]) + bf2f(px3);
    float f = 1.f / (1.f + __expf(-(gf + pf * c_val)));
    float i = 1.f / (1.f + __expf(-(gi + pi * c_val)));
    float ct = 2.f / (1.f + __expf(-2.f * gc)) - 1.f;
    float cn = f * c_val + i * ct;
    float o = 1.f / (1.f + __expf(-(go + po * cn)));
    float h = o * (2.f / (1.f + __expf(-2.f * cn)) - 1.f);
    c_val = cn;

    // ---- publish h ASAP: ONE tagged sc1 store per even thread, fire-and-forget ----
    if (t < 511) {
      float hx = __shfl_xor(h, 1);
      if ((u & 1) == 0) {
        u64 val = (u64)((unsigned)f2bf(h) | ((unsigned)f2bf(hx) << 16)) |
                  ((u64)(unsigned)(t + 1) << 32);
        u64* dst = tb + ((size_t)((t + 1) & 1) << 15) + ((size_t)bG << 9) +
                   (s << 2) + (u >> 1);
        __hip_atomic_store(dst, val, __ATOMIC_RELAXED, __HIP_MEMORY_SCOPE_AGENT);
      }
    }
    LGKM_BAR();  // sync#2: G(t) reads done before next iter's G writes

    // off critical path: out store (non-temporal) + next xp prefetch
    __builtin_nontemporal_store(h, &out[(size_t)(bG * 512 + t) * 1024 + n]);
    if (t < 511) {
      size_t xb = xbase0 + (size_t)(t + 1) * 262144;  // 64*4096
      px0 = xp[xb]; px1 = xp[xb + 1024]; px2 = xp[xb + 2048]; px3 = xp[xb + 3072];
    }
  }
}

// ---------------- launcher ----------------
extern "C" void kernel_launch(void* const* d_in, const int* in_sizes, int n_in,
                              void* d_out, int out_size, void* d_ws, size_t ws_size,
                              hipStream_t stream) {
  const float* x = (const float*)d_in[0];
  const float* c0 = (const float*)d_in[1];
  const float* h0 = (const float*)d_in[2];
  const float* Wfx = (const float*)d_in[3];
  const float* bfp = (const float*)d_in[4];
  const float* Wix = (const float*)d_in[5];
  const float* bip = (const float*)d_in[6];
  const float* Wox = (const float*)d_in[7];
  const float* bop = (const float*)d_in[8];
  const float* Wcx = (const float*)d_in[9];
  const float* bcp = (const float*)d_in[10];
  const float* Wfh = (const float*)d_in[11];
  const float* Wih = (const float*)d_in[12];
  const float* Woh = (const float*)d_in[13];
  const float* Wch = (const float*)d_in[14];
  const float* wcf = (const float*)d_in[15];
  const float* wci = (const float*)d_in[16];
  const float* wco = (const float*)d_in[17];
  float* out = (float*)d_out;

  char* ws = (char*)d_ws;
  ushort* xp = (ushort*)(ws + 0);              // 268,435,456 B
  ushort* WxT = (ushort*)(ws + 268435456ULL);  // 4,194,304 B (dead after gemm_xp)
  u64* tb = (u64*)(ws + 268435456ULL);         // 524,288 B, REUSES WxT region
  ushort* WhT = (ushort*)(ws + 272629760ULL);  // 8,388,608 B
  float* bias = (float*)(ws + 281018368ULL);   // 16,384 B
  if (ws_size < 281034752ULL) return;

  const float* wxs[4] = {Wfx, Wix, Wox, Wcx};
  for (int g = 0; g < 4; ++g)
    transpose_cvt<<<dim3(32, 16), dim3(32, 8), 0, stream>>>(
        wxs[g], WxT + (size_t)g * 1024 * 512, 512, 1024);
  const float* whs[4] = {Wfh, Wih, Woh, Wch};
  for (int g = 0; g < 4; ++g)
    transpose_cvt<<<dim3(32, 32), dim3(32, 8), 0, stream>>>(
        whs[g], WhT + (size_t)g * 1024 * 1024, 1024, 1024);
  concat_bias<<<16, 256, 0, stream>>>(bfp, bip, bop, bcp, bias);
  gemm_xp<<<dim3(32, 256), 256, 0, stream>>>(x, WxT, bias, xp);

  // WxT is dead now; its region becomes the tagged h buffer.
  hipMemsetAsync(tb, 0xFF, 524288, stream);              // tags -> 0xFFFFFFFF
  init_tagged<<<128, 256, 0, stream>>>(h0, (u64*)tb);    // parity 0 <- h0, tag 0

  void* args[8];
  args[0] = (void*)&xp;
  args[1] = (void*)&WhT;
  args[2] = (void*)&c0;
  args[3] = (void*)&wcf;
  args[4] = (void*)&wci;
  args[5] = (void*)&wco;
  args[6] = (void*)&tb;
  args[7] = (void*)&out;
  hipLaunchCooperativeKernel((void*)lstm_rec, dim3(256), dim3(256), args, 0, stream);
}